// Round 2
// baseline (105.308 us; speedup 1.0000x reference)
//
#include <hip/hip_runtime.h>

#define NN 4096
#define MM 4096
#define NEG 0.01f

// 256 threads = 4 waves per block; each wave computes TWO rows of W
// (shares the LDS c/r reads across both rows, doubles in-flight loads).
// Grid = NN/8 = 512 blocks -> 2 blocks/CU, 8 waves/CU.
__global__ __launch_bounds__(256, 2) void abstract_leaky_relu_kernel(
    const float* __restrict__ lbnd,
    const float* __restrict__ ubnd,
    const float* __restrict__ alpha,
    const float* __restrict__ W,
    const float* __restrict__ b,
    const float* __restrict__ l0,
    const float* __restrict__ u0,
    float* __restrict__ out)
{
    __shared__ float s_c[MM];  // center of input box
    __shared__ float s_r[MM];  // radius of input box

    for (int j = threadIdx.x; j < MM; j += 256) {
        float l = l0[j], u = u0[j];
        s_c[j] = 0.5f * (l + u);
        s_r[j] = 0.5f * (u - l);
    }
    __syncthreads();

    const int wave = threadIdx.x >> 6;
    const int lane = threadIdx.x & 63;
    const int row0 = blockIdx.x * 8 + wave * 2;   // this wave: rows row0, row0+1

    const float* __restrict__ Wr0 = W + (size_t)row0 * MM;
    const float* __restrict__ Wr1 = Wr0 + MM;

    float a1 = 0.0f, a2 = 0.0f;   // row0: W.c, |W|.r
    float c1 = 0.0f, c2 = 0.0f;   // row1: W.c, |W|.r

    #pragma unroll 4
    for (int j = lane * 4; j < MM; j += 64 * 4) {
        const float4 w0 = *(const float4*)(Wr0 + j);
        const float4 w1 = *(const float4*)(Wr1 + j);
        const float4 c  = *(const float4*)(s_c + j);
        const float4 r  = *(const float4*)(s_r + j);
        a1 += w0.x * c.x + w0.y * c.y + w0.z * c.z + w0.w * c.w;
        a2 += fabsf(w0.x) * r.x + fabsf(w0.y) * r.y +
              fabsf(w0.z) * r.z + fabsf(w0.w) * r.w;
        c1 += w1.x * c.x + w1.y * c.y + w1.z * c.z + w1.w * c.w;
        c2 += fabsf(w1.x) * r.x + fabsf(w1.y) * r.y +
              fabsf(w1.z) * r.z + fabsf(w1.w) * r.w;
    }

    // Wave-level butterfly reduction across 64 lanes.
    #pragma unroll
    for (int off = 32; off > 0; off >>= 1) {
        a1 += __shfl_down(a1, off);
        a2 += __shfl_down(a2, off);
        c1 += __shfl_down(c1, off);
        c2 += __shfl_down(c2, off);
    }

    if (lane == 0) {
        #pragma unroll
        for (int k = 0; k < 2; ++k) {
            const int row  = row0 + k;
            const float s1 = k ? c1 : a1;
            const float s2 = k ? c2 : a2;

            const float L = lbnd[row];
            const float U = ubnd[row];
            const float A = alpha[row];
            const float B = b[row];

            float lw = NEG, uw = NEG, ub_bias = 0.0f;
            if (L > 0.0f) {
                lw = 1.0f; uw = 1.0f;
            } else if (L < 0.0f && U > 0.0f) {
                const float slope = (U - NEG * L) / (U - L);
                uw = slope;
                ub_bias = (NEG - slope) * L;   // crossing-neuron upper intercept
                lw = fminf(fmaxf(A, NEG), 1.0f);
            }

            const float Pu = s1 + s2;   // max(W,0)@u0 + min(W,0)@l0
            const float Pl = s1 - s2;   // max(W,0)@l0 + min(W,0)@u0
            out[row]      = lw * (Pl + B);             // lower
            out[NN + row] = uw * (Pu + B) + ub_bias;   // upper (bias fix!)
        }
    }
}

extern "C" void kernel_launch(void* const* d_in, const int* in_sizes, int n_in,
                              void* d_out, int out_size, void* d_ws, size_t ws_size,
                              hipStream_t stream) {
    const float* lbnd  = (const float*)d_in[0];
    const float* ubnd  = (const float*)d_in[1];
    const float* alpha = (const float*)d_in[2];
    const float* W     = (const float*)d_in[3];
    const float* b     = (const float*)d_in[4];
    const float* l0    = (const float*)d_in[5];
    const float* u0    = (const float*)d_in[6];
    float* out = (float*)d_out;

    abstract_leaky_relu_kernel<<<NN / 8, 256, 0, stream>>>(
        lbnd, ubnd, alpha, W, b, l0, u0, out);
}